// Round 1
// 1011.690 us; speedup vs baseline: 2.1566x; 2.1566x over previous
//
#include <hip/hip_runtime.h>
#include <stdint.h>

typedef unsigned short u16;
typedef unsigned int u32;

// Problem constants
#define B_    2
#define S_    2048
#define NQ_   16
#define NKV_  4
#define DH_   128
#define DR_   64
#define DT_   192
#define M_    4096   // B_*S_

using short8 = __attribute__((ext_vector_type(8))) short;
using f32x4  = __attribute__((ext_vector_type(4))) float;

__device__ __forceinline__ float cl(float f) {   // clamp diagnostic: inf/NaN -> +-3.38e38 signature
    return fminf(fmaxf(f, -3.38e38f), 3.38e38f);
}
__device__ __forceinline__ u16 f2b(float f) {    // fp32 -> bf16 RNE
    union { float f; u32 u; } v; v.f = f;
    u32 u = v.u;
    return (u16)((u + 0x7fffu + ((u >> 16) & 1u)) >> 16);
}
__device__ __forceinline__ float b2f(u16 h) {    // bf16 -> fp32
    union { u32 u; float f; } v; v.u = ((u32)h) << 16;
    return v.f;
}
__device__ __forceinline__ short8 pack8(float4 a, float4 b, float s) {
    short8 r;
    r[0] = (short)f2b(a.x * s); r[1] = (short)f2b(a.y * s);
    r[2] = (short)f2b(a.z * s); r[3] = (short)f2b(a.w * s);
    r[4] = (short)f2b(b.x * s); r[5] = (short)f2b(b.y * s);
    r[6] = (short)f2b(b.z * s); r[7] = (short)f2b(b.w * s);
    return r;
}
// async global->LDS, 16B per lane. LDS dest is wave-uniform base + lane*16.
__device__ __forceinline__ void gload16(const u16* g, u16* l) {
    __builtin_amdgcn_global_load_lds(
        (const __attribute__((address_space(1))) void*)g,
        (__attribute__((address_space(3))) void*)l,
        16, 0, 0);
}

// ---------------------------------------------------------------------------
// OLD fp32 VALU GEMM (fallback path only): C[M][N] = A[M][K] @ W[K][N]
// ---------------------------------------------------------------------------
__global__ __launch_bounds__(256) void gemm_nt(const float* __restrict__ A,
                                               const float* __restrict__ W,
                                               float* __restrict__ C,
                                               int M, int N, int K) {
    __shared__ float lA[32][64];   // [k][m]
    __shared__ float lW[32][64];   // [k][n]
    const int tid = threadIdx.x;
    const int tx = tid & 15, ty = tid >> 4;
    const int m0 = blockIdx.y * 64, n0 = blockIdx.x * 64;
    float acc[4][4] = {};

    for (int kt = 0; kt < K; kt += 32) {
        __syncthreads();
#pragma unroll
        for (int c = 0; c < 2; ++c) {
            int sg = c * 256 + tid;
            int r = sg >> 3, c4 = (sg & 7) * 4;
            float4 v = *(const float4*)(A + (size_t)(m0 + r) * K + kt + c4);
            lA[c4 + 0][r] = v.x; lA[c4 + 1][r] = v.y;
            lA[c4 + 2][r] = v.z; lA[c4 + 3][r] = v.w;
        }
#pragma unroll
        for (int c = 0; c < 2; ++c) {
            int sg = c * 256 + tid;
            int rr = sg >> 4, n4 = (sg & 15) * 4;
            *(float4*)&lW[rr][n4] = *(const float4*)(W + (size_t)(kt + rr) * N + n0 + n4);
        }
        __syncthreads();
#pragma unroll
        for (int kk = 0; kk < 32; ++kk) {
            float4 a4 = *(const float4*)&lA[kk][ty * 4];
            float4 w4 = *(const float4*)&lW[kk][tx * 4];
            float a[4] = {a4.x, a4.y, a4.z, a4.w};
            float w[4] = {w4.x, w4.y, w4.z, w4.w};
#pragma unroll
            for (int i = 0; i < 4; ++i)
#pragma unroll
                for (int j = 0; j < 4; ++j)
                    acc[i][j] += a[i] * w[j];
        }
    }
#pragma unroll
    for (int i = 0; i < 4; ++i) {
        float* cp = C + (size_t)(m0 + ty * 4 + i) * N + n0 + tx * 4;
        float4 v = {cl(acc[i][0]), cl(acc[i][1]), cl(acc[i][2]), cl(acc[i][3])};
        *(float4*)cp = v;
    }
}

// ---------------------------------------------------------------------------
// Split fp32 -> (hi, lo) bf16, elementwise. 8 elems/thread; n must be /2048.
// ---------------------------------------------------------------------------
__global__ __launch_bounds__(256) void split_hl(const float* __restrict__ X,
                                                u16* __restrict__ H,
                                                u16* __restrict__ L) {
    size_t i = ((size_t)blockIdx.x * 256 + threadIdx.x) * 8;
    float4 a = *(const float4*)(X + i);
    float4 b4 = *(const float4*)(X + i + 4);
    float va[8] = {a.x, a.y, a.z, a.w, b4.x, b4.y, b4.z, b4.w};
    short8 h, l;
#pragma unroll
    for (int j = 0; j < 8; ++j) {
        u16 hh = f2b(va[j]);
        h[j] = (short)hh;
        l[j] = (short)f2b(va[j] - b2f(hh));
    }
    *(short8*)(H + i) = h;
    *(short8*)(L + i) = l;
}

// ---------------------------------------------------------------------------
// Weight transpose + split: W[K][N] fp32 -> Wt hi/lo [N][K] bf16.
// block (32,8), grid (K/32, N/32)
// ---------------------------------------------------------------------------
__global__ __launch_bounds__(256) void wt_split(const float* __restrict__ W,
                                                u16* __restrict__ Th,
                                                u16* __restrict__ Tl,
                                                int K, int N) {
    __shared__ float tile[32][33];
    int k0 = blockIdx.x * 32, n0 = blockIdx.y * 32;
    int tx = threadIdx.x, ty = threadIdx.y;
#pragma unroll
    for (int i = 0; i < 32; i += 8)
        tile[ty + i][tx] = W[(size_t)(k0 + ty + i) * N + n0 + tx];
    __syncthreads();
#pragma unroll
    for (int i = 0; i < 32; i += 8) {
        float v = tile[tx][ty + i];
        u16 hh = f2b(v);
        size_t o = (size_t)(n0 + ty + i) * K + k0 + tx;
        Th[o] = hh;
        Tl[o] = f2b(v - b2f(hh));
    }
}

// ---------------------------------------------------------------------------
// Split-bf16 MFMA GEMM (3-term error compensation):
//   C[m][n] = sum_k (Ah+Al)[m][k] * (Bh+Bl)[n][k]   (B stored transposed [N][K])
//   computed as Ah*Bh + Al*Bh + Ah*Bl, fp32 accumulate in MFMA.
// Block 256 = 4 waves (2x2), tile 128x128, BK=32, m97-style 2-barrier loop,
// global_load_lds width-16 staging, linear LDS [row][32] (conflict-free b128).
// M = 4096 fixed via gridDim.y = 32. Epilogue: fp32 C, or hi/lo bf16 (C==null).
// Layouts [m89/m91 verified, same as attn_mfma]: A-frag A[m=lane&15][k=quad*8+j],
// B-frag B[n=lane&15][k=quad*8+j], C/D col=lane&15, row=quad*4+reg.
// ---------------------------------------------------------------------------
__global__ __launch_bounds__(256) void gemm_bf3(const u16* __restrict__ Ah,
                                                const u16* __restrict__ Al,
                                                const u16* __restrict__ Bh,
                                                const u16* __restrict__ Bl,
                                                float* __restrict__ C,
                                                u16* __restrict__ Ch,
                                                u16* __restrict__ Cl,
                                                int N, int K) {
    __shared__ __align__(16) u16 lAh[128 * 32];
    __shared__ __align__(16) u16 lAl[128 * 32];
    __shared__ __align__(16) u16 lBh[128 * 32];
    __shared__ __align__(16) u16 lBl[128 * 32];
    const int t = threadIdx.x, lane = t & 63, w = t >> 6;
    const int quad = lane >> 4, l16 = lane & 15;
    const int wr = w >> 1, wc = w & 1;
    const int m0 = blockIdx.y * 128, n0 = blockIdx.x * 128;
    f32x4 acc[4][4] = {};

    for (int kt = 0; kt < K; kt += 32) {
        __syncthreads();
        // stage: each buffer = 128 rows x 32 bf16 = 512 x 16B chunks, 2/thread
#pragma unroll
        for (int c = 0; c < 2; ++c) {
            const int chunk = c * 256 + t;
            const int row = chunk >> 2, co = (chunk & 3) * 8;
            const int lofs = (c * 256 + w * 64) * 8;   // u16 units, wave-uniform
            const size_t ga = (size_t)(m0 + row) * K + kt + co;
            const size_t gb = (size_t)(n0 + row) * K + kt + co;
            gload16(Ah + ga, lAh + lofs);
            gload16(Al + ga, lAl + lofs);
            gload16(Bh + gb, lBh + lofs);
            gload16(Bl + gb, lBl + lofs);
        }
        __syncthreads();
        short8 af[4], ag[4], bf[4], bg[4];
#pragma unroll
        for (int i = 0; i < 4; ++i) {
            const int ar = (wr * 64 + i * 16 + l16) * 32 + quad * 8;
            const int br = (wc * 64 + i * 16 + l16) * 32 + quad * 8;
            af[i] = *(const short8*)&lAh[ar];
            ag[i] = *(const short8*)&lAl[ar];
            bf[i] = *(const short8*)&lBh[br];
            bg[i] = *(const short8*)&lBl[br];
        }
#pragma unroll
        for (int i = 0; i < 4; ++i)
#pragma unroll
            for (int j = 0; j < 4; ++j) {
                acc[i][j] = __builtin_amdgcn_mfma_f32_16x16x32_bf16(af[i], bf[j], acc[i][j], 0, 0, 0);
                acc[i][j] = __builtin_amdgcn_mfma_f32_16x16x32_bf16(ag[i], bf[j], acc[i][j], 0, 0, 0);
                acc[i][j] = __builtin_amdgcn_mfma_f32_16x16x32_bf16(af[i], bg[j], acc[i][j], 0, 0, 0);
            }
    }
    if (C) {
#pragma unroll
        for (int i = 0; i < 4; ++i)
#pragma unroll
            for (int j = 0; j < 4; ++j)
#pragma unroll
                for (int r = 0; r < 4; ++r)
                    C[(size_t)(m0 + wr * 64 + i * 16 + quad * 4 + r) * N +
                      n0 + wc * 64 + j * 16 + l16] = cl(acc[i][j][r]);
    } else {
#pragma unroll
        for (int i = 0; i < 4; ++i)
#pragma unroll
            for (int j = 0; j < 4; ++j)
#pragma unroll
                for (int r = 0; r < 4; ++r) {
                    size_t o = (size_t)(m0 + wr * 64 + i * 16 + quad * 4 + r) * N +
                               n0 + wc * 64 + j * 16 + l16;
                    float v = acc[i][j][r];
                    u16 hh = f2b(v);
                    Ch[o] = hh;
                    Cl[o] = f2b(v - b2f(hh));
                }
    }
}

// ---------------------------------------------------------------------------
// RoPE Q, in place on qr[(b,s)][h*64+d] (fp32)
// ---------------------------------------------------------------------------
__global__ __launch_bounds__(256) void rope_q_inplace(float* __restrict__ qr,
                                                      const float* __restrict__ cosc,
                                                      const float* __restrict__ sinc,
                                                      const int* __restrict__ pos) {
    int t = blockIdx.x * 256 + threadIdx.x;          // t < 4096*16*32
    int d = t & 31, h = (t >> 5) & 15, rowi = t >> 9;
    int s = rowi & 2047;
    int p = pos[s];
    float c1 = cosc[p * 64 + d],      s1 = sinc[p * 64 + d];
    float c2 = cosc[p * 64 + 32 + d], s2 = sinc[p * 64 + 32 + d];
    float* base = qr + (size_t)rowi * 1024 + h * 64;
    float x1 = base[d];
    float x2 = base[d + 32];
    base[d]      = x1 * c1 - x2 * s1;   // out = x*cos + rotate_half(x)*sin
    base[d + 32] = x2 * c2 + x1 * s2;
}

// RoPE K: krr[(b,s)][kv*64+d] -> Krope[b][kv][s][64]  (= Output 2)
__global__ __launch_bounds__(256) void rope_k(const float* __restrict__ krr,
                                              const float* __restrict__ cosc,
                                              const float* __restrict__ sinc,
                                              const int* __restrict__ pos,
                                              float* __restrict__ Krope) {
    int t = blockIdx.x * 256 + threadIdx.x;          // t < 4096*4*32
    int d = t & 31, kv = (t >> 5) & 3, rowi = t >> 7;
    int b = rowi >> 11, s = rowi & 2047;
    int p = pos[s];
    float c1 = cosc[p * 64 + d],      s1 = sinc[p * 64 + d];
    float c2 = cosc[p * 64 + 32 + d], s2 = sinc[p * 64 + 32 + d];
    float x1 = krr[(size_t)rowi * 256 + kv * 64 + d];
    float x2 = krr[(size_t)rowi * 256 + kv * 64 + 32 + d];
    size_t ob = ((size_t)((b * NKV_ + kv) * S_) + s) * 64;
    Krope[ob + d]      = cl(x1 * c1 - x2 * s1);
    Krope[ob + 32 + d] = cl(x2 * c2 + x1 * s2);
}

// ---------------------------------------------------------------------------
// pack_k: Kp bf16 [g=(b*4+kv)][s][192] <- kcb fp32 [(b,s)][kv*128+d] + krope fp32 [g][s][64]
// ---------------------------------------------------------------------------
__global__ __launch_bounds__(256) void pack_k(const float* __restrict__ kcb,
                                              const float* __restrict__ krope,
                                              u16* __restrict__ Kp) {
    int t = blockIdx.x * 256 + threadIdx.x;          // t < 16384*24
    int c8 = (t % 24) * 8;
    int r  = t / 24;                                  // r = g*2048 + s
    int g = r >> 11, s = r & 2047;
    int b = g >> 2, kv = g & 3;
    const float* src;
    if (c8 < 128) src = kcb + ((size_t)(b * S_ + s)) * 512 + kv * 128 + c8;
    else          src = krope + ((size_t)g * S_ + s) * 64 + (c8 - 128);
    float4 v0 = *(const float4*)src;
    float4 v1 = *(const float4*)(src + 4);
    short8 p = pack8(v0, v1, 1.f);
    *(short8*)(Kp + (size_t)r * 192 + c8) = p;
}

// ---------------------------------------------------------------------------
// transpose_vt: Vt bf16 [g][d=128][s=2048] <- vvb fp32 [(b,s)][kv*128+d]
// block (32,8), grid (64, 4, 8)
// ---------------------------------------------------------------------------
__global__ __launch_bounds__(256) void transpose_vt(const float* __restrict__ vvb,
                                                    u16* __restrict__ Vt) {
    __shared__ float tile[32][33];
    int s0 = blockIdx.x * 32, d0 = blockIdx.y * 32, g = blockIdx.z;
    int b = g >> 2, kv = g & 3;
    int tx = threadIdx.x, ty = threadIdx.y;
#pragma unroll
    for (int i = 0; i < 32; i += 8)
        tile[ty + i][tx] = vvb[((size_t)(b * S_ + s0 + ty + i)) * 512 + kv * 128 + d0 + tx];
    __syncthreads();
#pragma unroll
    for (int i = 0; i < 32; i += 8)
        Vt[((size_t)g * 128 + d0 + ty + i) * S_ + s0 + tx] = f2b(tile[tx][ty + i]);
}

// ---------------------------------------------------------------------------
// MFMA flash attention. Block = 4 waves = 64 q-rows of one (b,h).
// grid (32 qtiles [reversed: heavy first], 16 heads, 2 batch).
// Epilogue: fp32 (attf != null) or hi/lo bf16 split for the W_O gemm.
// ---------------------------------------------------------------------------
__global__ __launch_bounds__(256) void attn_mfma(const float* __restrict__ qc,
                                                 const float* __restrict__ qr,
                                                 const u16* __restrict__ Kp,
                                                 const u16* __restrict__ Vt,
                                                 float* __restrict__ attf,
                                                 u16* __restrict__ ah_out,
                                                 u16* __restrict__ al_out) {
    __shared__ __align__(16) u16 lK[32 * 200];     // 32 kv-rows x 192 (+8 pad)
    __shared__ __align__(16) u16 lVt[128 * 40];    // 128 d-rows x 32 (+8 pad)
    __shared__ __align__(16) u16 lP[4][16 * 40];   // per-wave P 16x32 (+8 pad)

    const int t = threadIdx.x, lane = t & 63, w = t >> 6;
    const int quad = lane >> 4, l16 = lane & 15;
    const int qt = 31 - (int)blockIdx.x;           // heavy blocks first
    const int h = blockIdx.y, b = blockIdx.z;
    const int g = b * NKV_ + (h >> 2);
    const int q0 = qt * 64;
    const int iw = q0 + w * 16;                    // wave's q-row base
    const float sc = 0.07216878364870322f;         // 1/sqrt(192)

    // Q fragments: rows m=l16, k-chunks of 32 (content 0..127, rope 128..191)
    short8 qf[6];
    {
        const int irow = iw + l16;
#pragma unroll
        for (int kc = 0; kc < 6; ++kc) {
            const float* src = (kc < 4)
                ? qc + ((size_t)(b * S_ + irow)) * 2048 + h * 128 + kc * 32 + quad * 8
                : qr + ((size_t)(b * S_ + irow)) * 1024 + h * 64 + (kc - 4) * 32 + quad * 8;
            float4 v0 = *(const float4*)src;
            float4 v1 = *(const float4*)(src + 4);
            qf[kc] = pack8(v0, v1, sc);
        }
    }

    f32x4 O8[8] = {};                               // O: n-chunks of d (8 x 16), C layout
    float mr[4] = {-1e30f, -1e30f, -1e30f, -1e30f};
    float lr[4] = {0.f, 0.f, 0.f, 0.f};

    const int ntile = qt * 2 + 2;
    for (int tile = 0; tile < ntile; ++tile) {
        const int j0 = tile * 32;
        __syncthreads();
        // stage K tile: 32 rows x 192 u16 = 768 x 16B, 3/thread
#pragma unroll
        for (int c = 0; c < 3; ++c) {
            int seg = c * 256 + t;
            int row = seg / 24, ch = (seg % 24) * 8;
            *(uint4*)&lK[row * 200 + ch] =
                *(const uint4*)&Kp[((size_t)g * S_ + j0 + row) * 192 + ch];
        }
        // stage Vt tile: 128 d-rows x 32 u16 = 512 x 16B, 2/thread
#pragma unroll
        for (int c = 0; c < 2; ++c) {
            int seg = c * 256 + t;
            int d = seg >> 2, ch = (seg & 3) * 8;
            *(uint4*)&lVt[d * 40 + ch] =
                *(const uint4*)&Vt[((size_t)g * 128 + d) * S_ + j0 + ch];
        }
        __syncthreads();

        if (j0 <= iw + 15) {                        // wave has unmasked rows
            // S = Q K^T for two 16-col chunks
            f32x4 s0 = {}, s1 = {};
#pragma unroll
            for (int kc = 0; kc < 6; ++kc) {
                short8 k0 = *(const short8*)&lK[l16 * 200 + kc * 32 + quad * 8];
                s0 = __builtin_amdgcn_mfma_f32_16x16x32_bf16(qf[kc], k0, s0, 0, 0, 0);
            }
#pragma unroll
            for (int kc = 0; kc < 6; ++kc) {
                short8 k1 = *(const short8*)&lK[(16 + l16) * 200 + kc * 32 + quad * 8];
                s1 = __builtin_amdgcn_mfma_f32_16x16x32_bf16(qf[kc], k1, s1, 0, 0, 0);
            }
            // causal mask; rows ir = iw + quad*4 + r, cols j0 + nc*16 + l16
            float sv[8];
#pragma unroll
            for (int r = 0; r < 4; ++r) {
                int ir = iw + quad * 4 + r;
                sv[r]     = (j0 + l16      <= ir) ? s0[r] : -1e30f;
                sv[4 + r] = (j0 + 16 + l16 <= ir) ? s1[r] : -1e30f;
            }
            // row max across the 16-lane group
            float tm[4];
#pragma unroll
            for (int r = 0; r < 4; ++r) tm[r] = fmaxf(sv[r], sv[4 + r]);
#pragma unroll
            for (int m = 1; m < 16; m <<= 1)
#pragma unroll
                for (int r = 0; r < 4; ++r) tm[r] = fmaxf(tm[r], __shfl_xor(tm[r], m));
            // online softmax update
            float al[4], p[8];
#pragma unroll
            for (int r = 0; r < 4; ++r) {
                float mn = fmaxf(mr[r], tm[r]);
                al[r] = __expf(mr[r] - mn);
                mr[r] = mn;
                p[r]     = __expf(sv[r] - mn);
                p[4 + r] = __expf(sv[4 + r] - mn);
            }
            float ps[4];
#pragma unroll
            for (int r = 0; r < 4; ++r) ps[r] = p[r] + p[4 + r];
#pragma unroll
            for (int m = 1; m < 16; m <<= 1)
#pragma unroll
                for (int r = 0; r < 4; ++r) ps[r] += __shfl_xor(ps[r], m);
#pragma unroll
            for (int r = 0; r < 4; ++r) lr[r] = lr[r] * al[r] + ps[r];
#pragma unroll
            for (int dc = 0; dc < 8; ++dc)
#pragma unroll
                for (int r = 0; r < 4; ++r) O8[dc][r] *= al[r];
            // P (C layout) -> LDS -> A-layout frag
#pragma unroll
            for (int r = 0; r < 4; ++r) {
                lP[w][(quad * 4 + r) * 40 + l16]      = f2b(p[r]);
                lP[w][(quad * 4 + r) * 40 + 16 + l16] = f2b(p[4 + r]);
            }
            short8 pf = *(const short8*)&lP[w][l16 * 40 + quad * 8];
            // O += P V  (B-frag from Vt rows: n=d, k=kv-pos)
#pragma unroll
            for (int dc = 0; dc < 8; ++dc) {
                short8 vf = *(const short8*)&lVt[(dc * 16 + l16) * 40 + quad * 8];
                O8[dc] = __builtin_amdgcn_mfma_f32_16x16x32_bf16(pf, vf, O8[dc], 0, 0, 0);
            }
        }
    }
    // epilogue: normalize, write fp32 or hi/lo bf16 split
    float inv[4];
#pragma unroll
    for (int r = 0; r < 4; ++r) inv[r] = 1.f / fmaxf(lr[r], 1e-30f);
    if (attf) {
#pragma unroll
        for (int dc = 0; dc < 8; ++dc)
#pragma unroll
            for (int r = 0; r < 4; ++r) {
                int ir = iw + quad * 4 + r;
                attf[((size_t)(b * S_ + ir)) * 2048 + h * 128 + dc * 16 + l16] =
                    cl(O8[dc][r] * inv[r]);
            }
    } else {
#pragma unroll
        for (int dc = 0; dc < 8; ++dc)
#pragma unroll
            for (int r = 0; r < 4; ++r) {
                int ir = iw + quad * 4 + r;
                size_t o = ((size_t)(b * S_ + ir)) * 2048 + h * 128 + dc * 16 + l16;
                float v = cl(O8[dc][r] * inv[r]);
                u16 hh = f2b(v);
                ah_out[o] = hh;
                al_out[o] = f2b(v - b2f(hh));
            }
    }
}

// ---------------------------------------------------------------------------
extern "C" void kernel_launch(void* const* d_in, const int* in_sizes, int n_in,
                              void* d_out, int out_size, void* d_ws, size_t ws_size,
                              hipStream_t stream) {
    const float* x     = (const float*)d_in[0];
    const float* cosc  = (const float*)d_in[1];
    const float* sinc  = (const float*)d_in[2];
    const int*   pos   = (const int*)d_in[3];
    // d_in[4] = attn_mask (causal tril) -- implemented analytically
    const float* W_DKV = (const float*)d_in[5];
    const float* W_UK  = (const float*)d_in[6];
    const float* W_UV  = (const float*)d_in[7];
    const float* W_DQ  = (const float*)d_in[8];
    const float* W_UQ  = (const float*)d_in[9];
    const float* W_KR  = (const float*)d_in[10];
    const float* W_QR  = (const float*)d_in[11];
    const float* W_O   = (const float*)d_in[12];

    float* outp      = (float*)d_out;            // [B,S,2048]
    float* ckv_out   = outp + 8388608;           // [B,S,512]
    float* krope_out = outp + 10485760;          // [B,NKV,S,64]

    const size_t NEED_NEW = 241172480;           // bytes for MFMA path

    if (ws_size >= NEED_NEW) {
        // ---- split-bf16 MFMA path ----
        char* w = (char*)d_ws;
        auto alloc = [&](size_t bytes) { char* p = w; w += bytes; return p; };
        float* qcb = (float*)alloc(33554432);    // [4096][2048] Q content fp32
        float* qrr = (float*)alloc(16777216);    // [4096][1024]
        float* krr = (float*)alloc(4194304);     // [4096][256]
        float* kcb = (float*)alloc(8388608);     // [4096][512]
        float* vvb = (float*)alloc(8388608);     // [4096][512]
        u16* Kp  = (u16*)alloc(6291456);         // [8][2048][192] bf16
        u16* Vt  = (u16*)alloc(4194304);         // [8][128][2048] bf16
        u16* xh  = (u16*)alloc(16777216);        // x hi/lo [4096][2048]
        u16* xl  = (u16*)alloc(16777216);
        u16* cqh = (u16*)alloc(12582912);        // c_q hi/lo [4096][1536]
        u16* cql = (u16*)alloc(12582912);
        u16* ckh = (u16*)alloc(4194304);         // c_kv hi/lo [4096][512]
        u16* ckl = (u16*)alloc(4194304);
        u16* ath = (u16*)alloc(16777216);        // attn hi/lo [4096][2048]
        u16* atl = (u16*)alloc(16777216);
        // transposed+split weights [N][K] bf16
        u16* Wdkvh = (u16*)alloc(2097152); u16* Wdkvl = (u16*)alloc(2097152); // [512][2048]
        u16* Wkrh  = (u16*)alloc(1048576); u16* Wkrl  = (u16*)alloc(1048576); // [256][2048]
        u16* Wdqh  = (u16*)alloc(6291456); u16* Wdql  = (u16*)alloc(6291456); // [1536][2048]
        u16* Wuqh  = (u16*)alloc(6291456); u16* Wuql  = (u16*)alloc(6291456); // [2048][1536]
        u16* Wqrh  = (u16*)alloc(4194304); u16* Wqrl  = (u16*)alloc(4194304); // [1024][2048]
        u16* Wukh  = (u16*)alloc(524288);  u16* Wukl  = (u16*)alloc(524288);  // [512][512]
        u16* Wuvh  = (u16*)alloc(524288);  u16* Wuvl  = (u16*)alloc(524288);  // [512][512]
        u16* Woh   = (u16*)alloc(8388608); u16* Wol   = (u16*)alloc(8388608); // [2048][2048]

        const dim3 tb(32, 8);
        wt_split<<<dim3(64, 16), tb, 0, stream>>>(W_DKV, Wdkvh, Wdkvl, 2048, 512);
        wt_split<<<dim3(64, 8),  tb, 0, stream>>>(W_KR,  Wkrh,  Wkrl,  2048, 256);
        wt_split<<<dim3(64, 48), tb, 0, stream>>>(W_DQ,  Wdqh,  Wdql,  2048, 1536);
        wt_split<<<dim3(48, 64), tb, 0, stream>>>(W_UQ,  Wuqh,  Wuql,  1536, 2048);
        wt_split<<<dim3(64, 32), tb, 0, stream>>>(W_QR,  Wqrh,  Wqrl,  2048, 1024);
        wt_split<<<dim3(16, 16), tb, 0, stream>>>(W_UK,  Wukh,  Wukl,  512,  512);
        wt_split<<<dim3(16, 16), tb, 0, stream>>>(W_UV,  Wuvh,  Wuvl,  512,  512);
        wt_split<<<dim3(64, 64), tb, 0, stream>>>(W_O,   Woh,   Wol,   2048, 2048);
        split_hl<<<4096, 256, 0, stream>>>(x, xh, xl);                 // [4096][2048]

        // projections (all C = A @ Wt^T, M=4096 via gridDim.y=32)
        gemm_bf3<<<dim3(4, 32),  256, 0, stream>>>(xh, xl, Wdkvh, Wdkvl, ckv_out, nullptr, nullptr, 512, 2048);  // c_kv (Output 1)
        split_hl<<<1024, 256, 0, stream>>>(ckv_out, ckh, ckl);          // [4096][512]
        gemm_bf3<<<dim3(2, 32),  256, 0, stream>>>(xh, xl, Wkrh, Wkrl, krr, nullptr, nullptr, 256, 2048);        // K rope raw
        gemm_bf3<<<dim3(12, 32), 256, 0, stream>>>(xh, xl, Wdqh, Wdql, nullptr, cqh, cql, 1536, 2048);           // c_q -> hi/lo
        gemm_bf3<<<dim3(16, 32), 256, 0, stream>>>(cqh, cql, Wuqh, Wuql, qcb, nullptr, nullptr, 2048, 1536);     // Q content
        gemm_bf3<<<dim3(8, 32),  256, 0, stream>>>(xh, xl, Wqrh, Wqrl, qrr, nullptr, nullptr, 1024, 2048);       // Q rope raw
        gemm_bf3<<<dim3(4, 32),  256, 0, stream>>>(ckh, ckl, Wukh, Wukl, kcb, nullptr, nullptr, 512, 512);       // K content
        gemm_bf3<<<dim3(4, 32),  256, 0, stream>>>(ckh, ckl, Wuvh, Wuvl, vvb, nullptr, nullptr, 512, 512);       // V

        // rope
        rope_q_inplace<<<8192, 256, 0, stream>>>(qrr, cosc, sinc, pos);
        rope_k<<<2048, 256, 0, stream>>>(krr, cosc, sinc, pos, krope_out);              // Output 2

        // pack K / V for MFMA attention
        pack_k<<<1536, 256, 0, stream>>>(kcb, krope_out, Kp);
        transpose_vt<<<dim3(64, 4, 8), dim3(32, 8), 0, stream>>>(vvb, Vt);

        // attention (writes hi/lo bf16 directly) + output projection
        attn_mfma<<<dim3(32, 16, 2), 256, 0, stream>>>(qcb, qrr, Kp, Vt, nullptr, ath, atl);
        gemm_bf3<<<dim3(16, 32), 256, 0, stream>>>(ath, atl, Woh, Wol, outp, nullptr, nullptr, 2048, 2048);      // Output 0
    } else {
        // ---- fallback: previous fp32 VALU path ----
        char* w = (char*)d_ws;
        auto alloc = [&](size_t bytes) { char* p = w; w += bytes; return p; };
        float* cqb   = (float*)alloc(25165824);  // [4096][1536]
        float* qcb   = (float*)alloc(33554432);  // [4096][2048]
        float* qrr   = (float*)alloc(16777216);  // [4096][1024]
        float* krr   = (float*)alloc(4194304);   // [4096][256]
        float* kcb   = (float*)alloc(8388608);   // [4096][512]
        float* vvb   = (float*)alloc(8388608);   // [4096][512]
        float* attnb = (float*)alloc(33554432);  // [4096][2048]
        u16*   Kp    = (u16*)alloc(6291456);     // [8][2048][192] bf16
        u16*   Vt    = (u16*)alloc(4194304);     // [8][128][2048] bf16

        gemm_nt<<<dim3(8, 64),  256, 0, stream>>>(x,       W_DKV, ckv_out, M_, 512,  2048);
        gemm_nt<<<dim3(4, 64),  256, 0, stream>>>(x,       W_KR,  krr,     M_, 256,  2048);
        gemm_nt<<<dim3(24, 64), 256, 0, stream>>>(x,       W_DQ,  cqb,     M_, 1536, 2048);
        gemm_nt<<<dim3(32, 64), 256, 0, stream>>>(cqb,     W_UQ,  qcb,     M_, 2048, 1536);
        gemm_nt<<<dim3(16, 64), 256, 0, stream>>>(x,       W_QR,  qrr,     M_, 1024, 2048);
        gemm_nt<<<dim3(8, 64),  256, 0, stream>>>(ckv_out, W_UK,  kcb,     M_, 512,  512);
        gemm_nt<<<dim3(8, 64),  256, 0, stream>>>(ckv_out, W_UV,  vvb,     M_, 512,  512);

        rope_q_inplace<<<8192, 256, 0, stream>>>(qrr, cosc, sinc, pos);
        rope_k<<<2048, 256, 0, stream>>>(krr, cosc, sinc, pos, krope_out);

        pack_k<<<1536, 256, 0, stream>>>(kcb, krope_out, Kp);
        transpose_vt<<<dim3(64, 4, 8), dim3(32, 8), 0, stream>>>(vvb, Vt);

        attn_mfma<<<dim3(32, 16, 2), 256, 0, stream>>>(qcb, qrr, Kp, Vt, attnb, nullptr, nullptr);
        gemm_nt<<<dim3(32, 64), 256, 0, stream>>>(attnb, W_O, outp, M_, 2048, 2048);
    }
}

// Round 3
// 609.904 us; speedup vs baseline: 3.5774x; 1.6588x over previous
//
#include <hip/hip_runtime.h>
#include <stdint.h>

typedef unsigned short u16;
typedef unsigned int u32;

// Problem constants
#define B_    2
#define S_    2048
#define NQ_   16
#define NKV_  4
#define DH_   128
#define DR_   64
#define DT_   192
#define M_    4096   // B_*S_

using short8 = __attribute__((ext_vector_type(8))) short;
using f32x4  = __attribute__((ext_vector_type(4))) float;
using half8  = __attribute__((ext_vector_type(8))) _Float16;

__device__ __forceinline__ float cl(float f) {   // clamp diagnostic: inf/NaN -> +-3.38e38 signature
    return fminf(fmaxf(f, -3.38e38f), 3.38e38f);
}
__device__ __forceinline__ u16 f2b(float f) {    // fp32 -> bf16 RNE
    union { float f; u32 u; } v; v.f = f;
    u32 u = v.u;
    return (u16)((u + 0x7fffu + ((u >> 16) & 1u)) >> 16);
}
__device__ __forceinline__ float b2f(u16 h) {    // bf16 -> fp32
    union { u32 u; float f; } v; v.u = ((u32)h) << 16;
    return v.f;
}
__device__ __forceinline__ short8 pack8(float4 a, float4 b, float s) {
    short8 r;
    r[0] = (short)f2b(a.x * s); r[1] = (short)f2b(a.y * s);
    r[2] = (short)f2b(a.z * s); r[3] = (short)f2b(a.w * s);
    r[4] = (short)f2b(b.x * s); r[5] = (short)f2b(b.y * s);
    r[6] = (short)f2b(b.z * s); r[7] = (short)f2b(b.w * s);
    return r;
}
// async global->LDS, 16B per lane. LDS dest is wave-uniform base + lane*16.
__device__ __forceinline__ void gload16(const void* g, void* l) {
    __builtin_amdgcn_global_load_lds(
        (const __attribute__((address_space(1))) void*)g,
        (__attribute__((address_space(3))) void*)l,
        16, 0, 0);
}

// ---------------------------------------------------------------------------
// x_prep: x fp32 -> xh/xl bf16 hi/lo (for exact-path gemm) + xf fp16
// ---------------------------------------------------------------------------
__global__ __launch_bounds__(256) void x_prep(const float* __restrict__ X,
                                              u16* __restrict__ H,
                                              u16* __restrict__ L,
                                              _Float16* __restrict__ F) {
    size_t i = ((size_t)blockIdx.x * 256 + threadIdx.x) * 8;
    float4 a = *(const float4*)(X + i);
    float4 b4 = *(const float4*)(X + i + 4);
    float va[8] = {a.x, a.y, a.z, a.w, b4.x, b4.y, b4.z, b4.w};
    short8 h, l;
    half8 f;
#pragma unroll
    for (int j = 0; j < 8; ++j) {
        u16 hh = f2b(va[j]);
        h[j] = (short)hh;
        l[j] = (short)f2b(va[j] - b2f(hh));
        f[j] = (_Float16)va[j];
    }
    *(short8*)(H + i) = h;
    *(short8*)(L + i) = l;
    *(half8*)(F + i) = f;
}

// ---------------------------------------------------------------------------
// Weight transpose + bf16 hi/lo split: W[K][N] fp32 -> Th/Tl [N][K] bf16.
// block (32,8), grid (K/32, N/32)
// ---------------------------------------------------------------------------
__global__ __launch_bounds__(256) void wt_split(const float* __restrict__ W,
                                                u16* __restrict__ Th,
                                                u16* __restrict__ Tl,
                                                int K, int N) {
    __shared__ float tile[32][33];
    int k0 = blockIdx.x * 32, n0 = blockIdx.y * 32;
    int tx = threadIdx.x, ty = threadIdx.y;
#pragma unroll
    for (int i = 0; i < 32; i += 8)
        tile[ty + i][tx] = W[(size_t)(k0 + ty + i) * N + n0 + tx];
    __syncthreads();
#pragma unroll
    for (int i = 0; i < 32; i += 8) {
        float v = tile[tx][ty + i];
        u16 hh = f2b(v);
        size_t o = (size_t)(n0 + ty + i) * K + k0 + tx;
        Th[o] = hh;
        Tl[o] = f2b(v - b2f(hh));
    }
}

// Weight transpose to fp16: W[K][N] fp32 -> T [N][K] fp16.
__global__ __launch_bounds__(256) void wt_f16(const float* __restrict__ W,
                                              _Float16* __restrict__ T,
                                              int K, int N) {
    __shared__ float tile[32][33];
    int k0 = blockIdx.x * 32, n0 = blockIdx.y * 32;
    int tx = threadIdx.x, ty = threadIdx.y;
#pragma unroll
    for (int i = 0; i < 32; i += 8)
        tile[ty + i][tx] = W[(size_t)(k0 + ty + i) * N + n0 + tx];
    __syncthreads();
#pragma unroll
    for (int i = 0; i < 32; i += 8)
        T[(size_t)(n0 + ty + i) * K + k0 + tx] = (_Float16)tile[tx][ty + i];
}

// ---------------------------------------------------------------------------
// Split-bf16 MFMA GEMM (3-term error compensation), used for direct outputs:
//   C[m][n] = Ah*Bh + Al*Bh + Ah*Bl   (B stored transposed [N][K]), fp32 out.
// Tile 128x128, BK=32, 4 waves (2x2), global_load_lds staging. [verified r1]
// ---------------------------------------------------------------------------
__global__ __launch_bounds__(256) void gemm_bf3(const u16* __restrict__ Ah,
                                                const u16* __restrict__ Al,
                                                const u16* __restrict__ Bh,
                                                const u16* __restrict__ Bl,
                                                float* __restrict__ C,
                                                int N, int K) {
    __shared__ __align__(16) u16 lAh[128 * 32];
    __shared__ __align__(16) u16 lAl[128 * 32];
    __shared__ __align__(16) u16 lBh[128 * 32];
    __shared__ __align__(16) u16 lBl[128 * 32];
    const int t = threadIdx.x, lane = t & 63, w = t >> 6;
    const int quad = lane >> 4, l16 = lane & 15;
    const int wr = w >> 1, wc = w & 1;
    const int m0 = blockIdx.y * 128, n0 = blockIdx.x * 128;
    f32x4 acc[4][4] = {};

    for (int kt = 0; kt < K; kt += 32) {
        __syncthreads();
#pragma unroll
        for (int c = 0; c < 2; ++c) {
            const int chunk = c * 256 + t;
            const int row = chunk >> 2, co = (chunk & 3) * 8;
            const int lofs = (c * 256 + w * 64) * 8;   // u16 units, wave-uniform
            const size_t ga = (size_t)(m0 + row) * K + kt + co;
            const size_t gb = (size_t)(n0 + row) * K + kt + co;
            gload16(Ah + ga, lAh + lofs);
            gload16(Al + ga, lAl + lofs);
            gload16(Bh + gb, lBh + lofs);
            gload16(Bl + gb, lBl + lofs);
        }
        __syncthreads();
        short8 af[4], ag[4], bf[4], bg[4];
#pragma unroll
        for (int i = 0; i < 4; ++i) {
            const int ar = (wr * 64 + i * 16 + l16) * 32 + quad * 8;
            const int br = (wc * 64 + i * 16 + l16) * 32 + quad * 8;
            af[i] = *(const short8*)&lAh[ar];
            ag[i] = *(const short8*)&lAl[ar];
            bf[i] = *(const short8*)&lBh[br];
            bg[i] = *(const short8*)&lBl[br];
        }
#pragma unroll
        for (int i = 0; i < 4; ++i)
#pragma unroll
            for (int j = 0; j < 4; ++j) {
                acc[i][j] = __builtin_amdgcn_mfma_f32_16x16x32_bf16(af[i], bf[j], acc[i][j], 0, 0, 0);
                acc[i][j] = __builtin_amdgcn_mfma_f32_16x16x32_bf16(ag[i], bf[j], acc[i][j], 0, 0, 0);
                acc[i][j] = __builtin_amdgcn_mfma_f32_16x16x32_bf16(af[i], bg[j], acc[i][j], 0, 0, 0);
            }
    }
#pragma unroll
    for (int i = 0; i < 4; ++i)
#pragma unroll
        for (int j = 0; j < 4; ++j)
#pragma unroll
            for (int r = 0; r < 4; ++r)
                C[(size_t)(m0 + wr * 64 + i * 16 + quad * 4 + r) * N +
                  n0 + wc * 64 + j * 16 + l16] = cl(acc[i][j][r]);
}

// ---------------------------------------------------------------------------
// fp16 single-pass MFMA GEMM (attention path; fp16 input err ~2^-11 is
// negligible vs downstream bf16 packs). Same structure/layout as gemm_bf3
// but 1 MFMA term and 2 LDS buffers. Epilogue modes:
//   C  != null : fp32
//   Cf != null : fp16
//   else       : bf16 scaled by cscale (pre-scaled Q for attention)
// ---------------------------------------------------------------------------
__global__ __launch_bounds__(256) void gemm_f16(const _Float16* __restrict__ A,
                                                const _Float16* __restrict__ Bt,
                                                float* __restrict__ C,
                                                _Float16* __restrict__ Cf,
                                                u16* __restrict__ Cb, float cscale,
                                                int N, int K) {
    __shared__ __align__(16) _Float16 lA[128 * 32];
    __shared__ __align__(16) _Float16 lB[128 * 32];
    const int t = threadIdx.x, lane = t & 63, w = t >> 6;
    const int quad = lane >> 4, l16 = lane & 15;
    const int wr = w >> 1, wc = w & 1;
    const int m0 = blockIdx.y * 128, n0 = blockIdx.x * 128;
    f32x4 acc[4][4] = {};

    for (int kt = 0; kt < K; kt += 32) {
        __syncthreads();
#pragma unroll
        for (int c = 0; c < 2; ++c) {
            const int chunk = c * 256 + t;
            const int row = chunk >> 2, co = (chunk & 3) * 8;
            const int lofs = (c * 256 + w * 64) * 8;   // fp16 units, wave-uniform
            gload16(A + (size_t)(m0 + row) * K + kt + co, lA + lofs);
            gload16(Bt + (size_t)(n0 + row) * K + kt + co, lB + lofs);
        }
        __syncthreads();
        half8 af[4], bf4[4];
#pragma unroll
        for (int i = 0; i < 4; ++i) {
            af[i]  = *(const half8*)&lA[(wr * 64 + i * 16 + l16) * 32 + quad * 8];
            bf4[i] = *(const half8*)&lB[(wc * 64 + i * 16 + l16) * 32 + quad * 8];
        }
#pragma unroll
        for (int i = 0; i < 4; ++i)
#pragma unroll
            for (int j = 0; j < 4; ++j)
                acc[i][j] = __builtin_amdgcn_mfma_f32_16x16x32_f16(af[i], bf4[j], acc[i][j], 0, 0, 0);
    }
#pragma unroll
    for (int i = 0; i < 4; ++i)
#pragma unroll
        for (int j = 0; j < 4; ++j)
#pragma unroll
            for (int r = 0; r < 4; ++r) {
                size_t o = (size_t)(m0 + wr * 64 + i * 16 + quad * 4 + r) * N +
                           n0 + wc * 64 + j * 16 + l16;
                float v = acc[i][j][r];
                if (C)       C[o] = cl(v);
                else if (Cf) Cf[o] = (_Float16)v;
                else         Cb[o] = f2b(v * cscale);
            }
}

// ---------------------------------------------------------------------------
// ckv_post: Cdk fp32 [4096][768] cols 0..511 -> ckv_out fp32 + ckf fp16
// ---------------------------------------------------------------------------
__global__ __launch_bounds__(256) void ckv_post(const float* __restrict__ Cdk,
                                                float* __restrict__ ckv,
                                                _Float16* __restrict__ ckf) {
    int i = blockIdx.x * 256 + threadIdx.x;          // 0..131071
    int row = i >> 6, c8 = (i & 63) * 8;
    const float* src = Cdk + (size_t)row * 768 + c8;
    float4 a = *(const float4*)src;
    float4 b4 = *(const float4*)(src + 4);
    *(float4*)(ckv + (size_t)row * 512 + c8) = a;
    *(float4*)(ckv + (size_t)row * 512 + c8 + 4) = b4;
    float va[8] = {a.x, a.y, a.z, a.w, b4.x, b4.y, b4.z, b4.w};
    half8 f;
#pragma unroll
    for (int j = 0; j < 8; ++j) f[j] = (_Float16)va[j];
    *(half8*)(ckf + (size_t)row * 512 + c8) = f;
}

// ---------------------------------------------------------------------------
// RoPE Q, in place on qr[(b,s)][h*64+d] (fp32)
// ---------------------------------------------------------------------------
__global__ __launch_bounds__(256) void rope_q_inplace(float* __restrict__ qr,
                                                      const float* __restrict__ cosc,
                                                      const float* __restrict__ sinc,
                                                      const int* __restrict__ pos) {
    int t = blockIdx.x * 256 + threadIdx.x;          // t < 4096*16*32
    int d = t & 31, h = (t >> 5) & 15, rowi = t >> 9;
    int s = rowi & 2047;
    int p = pos[s];
    float c1 = cosc[p * 64 + d],      s1 = sinc[p * 64 + d];
    float c2 = cosc[p * 64 + 32 + d], s2 = sinc[p * 64 + 32 + d];
    float* base = qr + (size_t)rowi * 1024 + h * 64;
    float x1 = base[d];
    float x2 = base[d + 32];
    base[d]      = x1 * c1 - x2 * s1;   // out = x*cos + rotate_half(x)*sin
    base[d + 32] = x2 * c2 + x1 * s2;
}

// RoPE K: krr[(b,s)][ldk stride, kv*64+d] -> Krope[b][kv][s][64]  (= Output 2)
__global__ __launch_bounds__(256) void rope_k(const float* __restrict__ krr, int ldk,
                                              const float* __restrict__ cosc,
                                              const float* __restrict__ sinc,
                                              const int* __restrict__ pos,
                                              float* __restrict__ Krope) {
    int t = blockIdx.x * 256 + threadIdx.x;          // t < 4096*4*32
    int d = t & 31, kv = (t >> 5) & 3, rowi = t >> 7;
    int b = rowi >> 11, s = rowi & 2047;
    int p = pos[s];
    float c1 = cosc[p * 64 + d],      s1 = sinc[p * 64 + d];
    float c2 = cosc[p * 64 + 32 + d], s2 = sinc[p * 64 + 32 + d];
    float x1 = krr[(size_t)rowi * ldk + kv * 64 + d];
    float x2 = krr[(size_t)rowi * ldk + kv * 64 + 32 + d];
    size_t ob = ((size_t)((b * NKV_ + kv) * S_) + s) * 64;
    Krope[ob + d]      = cl(x1 * c1 - x2 * s1);
    Krope[ob + 32 + d] = cl(x2 * c2 + x1 * s2);
}

// ---------------------------------------------------------------------------
// pack_k: Kp bf16 [g=(b*4+kv)][s][192] <- kcb fp32 [(b,s)][ldkc, kv*128+d]
//         + krope fp32 [g][s][64]
// ---------------------------------------------------------------------------
__global__ __launch_bounds__(256) void pack_k(const float* __restrict__ kcb, int ldkc,
                                              const float* __restrict__ krope,
                                              u16* __restrict__ Kp) {
    int t = blockIdx.x * 256 + threadIdx.x;          // t < 16384*24
    int c8 = (t % 24) * 8;
    int r  = t / 24;                                  // r = g*2048 + s
    int g = r >> 11, s = r & 2047;
    int b = g >> 2, kv = g & 3;
    const float* src;
    if (c8 < 128) src = kcb + ((size_t)(b * S_ + s)) * ldkc + kv * 128 + c8;
    else          src = krope + ((size_t)g * S_ + s) * 64 + (c8 - 128);
    float4 v0 = *(const float4*)src;
    float4 v1 = *(const float4*)(src + 4);
    short8 p = pack8(v0, v1, 1.f);
    *(short8*)(Kp + (size_t)r * 192 + c8) = p;
}

// ---------------------------------------------------------------------------
// transpose_vt: Vt bf16 [g][d=128][s=2048] <- vvb fp32 [(b,s)][ldv, kv*128+d]
// block (32,8), grid (64, 4, 8)
// ---------------------------------------------------------------------------
__global__ __launch_bounds__(256) void transpose_vt(const float* __restrict__ vvb, int ldv,
                                                    u16* __restrict__ Vt) {
    __shared__ float tile[32][33];
    int s0 = blockIdx.x * 32, d0 = blockIdx.y * 32, g = blockIdx.z;
    int b = g >> 2, kv = g & 3;
    int tx = threadIdx.x, ty = threadIdx.y;
#pragma unroll
    for (int i = 0; i < 32; i += 8)
        tile[ty + i][tx] = vvb[((size_t)(b * S_ + s0 + ty + i)) * ldv + kv * 128 + d0 + tx];
    __syncthreads();
#pragma unroll
    for (int i = 0; i < 32; i += 8)
        Vt[((size_t)g * 128 + d0 + ty + i) * S_ + s0 + tx] = f2b(tile[tx][ty + i]);
}

// ---------------------------------------------------------------------------
// MFMA flash attention. Block = 4 waves = 64 q-rows of one (b,h).
// KV tile = 64. Paired q-tiles for causal balance: block px handles
// qt = 31-px then qt = px  ->  (32-px) + (px+1) = 33 tiles per block, uniform.
// grid (16, 16, 2) = 512 blocks = 2/CU, all equal work.
// Q content from qc16 (bf16, pre-scaled by 1/sqrt(192) in UQ epilogue);
// Q rope from qrr fp32 (packed here). Out: atf fp16 [(b,s)][h*128+d].
// Layouts [m89/m91 verified]: A-frag A[m=lane&15][k=quad*8+j];
// B-frag B[n=lane&15][k=quad*8+j]; C/D col=lane&15, row=quad*4+reg.
// ---------------------------------------------------------------------------
__global__ __launch_bounds__(256) void attn_mfma(const u16* __restrict__ qc16,
                                                 const float* __restrict__ qr,
                                                 const u16* __restrict__ Kp,
                                                 const u16* __restrict__ Vt,
                                                 _Float16* __restrict__ atf) {
    __shared__ __align__(16) u16 lK[64 * 200];     // 64 kv-rows x 192 (+8 pad)
    __shared__ __align__(16) u16 lVt[128 * 72];    // 128 d-rows x 64 (+8 pad)
    __shared__ __align__(16) u16 lP[4][16 * 72];   // per-wave P 16x64 (+8 pad)

    const int t = threadIdx.x, lane = t & 63, w = t >> 6;
    const int quad = lane >> 4, l16 = lane & 15;
    const int px = blockIdx.x, h = blockIdx.y, b = blockIdx.z;
    const int g = b * NKV_ + (h >> 2);
    const float sc = 0.07216878364870322f;         // 1/sqrt(192)

    for (int ph = 0; ph < 2; ++ph) {
        const int qt = ph ? px : (31 - px);        // heavy tile first
        const int q0 = qt * 64;
        const int iw = q0 + w * 16;                // wave's q-row base

        // Q fragments: rows m=l16; content (bf16 pre-scaled) + rope (fp32->bf16)
        short8 qf[6];
        {
            const int irow = iw + l16;
#pragma unroll
            for (int kc = 0; kc < 4; ++kc)
                qf[kc] = *(const short8*)&qc16[((size_t)(b * S_ + irow)) * 2048 +
                                               h * 128 + kc * 32 + quad * 8];
#pragma unroll
            for (int kc = 4; kc < 6; ++kc) {
                const float* src = qr + ((size_t)(b * S_ + irow)) * 1024 +
                                   h * 64 + (kc - 4) * 32 + quad * 8;
                float4 v0 = *(const float4*)src;
                float4 v1 = *(const float4*)(src + 4);
                qf[kc] = pack8(v0, v1, sc);
            }
        }

        f32x4 O8[8] = {};
        float mr[4] = {-1e30f, -1e30f, -1e30f, -1e30f};
        float lr[4] = {0.f, 0.f, 0.f, 0.f};

        const int ntile = qt + 1;
        for (int tile = 0; tile < ntile; ++tile) {
            const int j0 = tile * 64;
            __syncthreads();
            // stage K tile: 64 rows x 192 u16 = 1536 x 16B, 6/thread
#pragma unroll
            for (int c = 0; c < 6; ++c) {
                int seg = c * 256 + t;
                int row = seg / 24, ch = (seg % 24) * 8;
                *(uint4*)&lK[row * 200 + ch] =
                    *(const uint4*)&Kp[((size_t)g * S_ + j0 + row) * 192 + ch];
            }
            // stage Vt tile: 128 d-rows x 64 u16 = 1024 x 16B, 4/thread
#pragma unroll
            for (int c = 0; c < 4; ++c) {
                int seg = c * 256 + t;
                int d = seg >> 3, ch = (seg & 7) * 8;
                *(uint4*)&lVt[d * 72 + ch] =
                    *(const uint4*)&Vt[((size_t)g * 128 + d) * S_ + j0 + ch];
            }
            __syncthreads();

            // S = Q K^T, four 16-col chunks
            f32x4 s4[4];
            __builtin_amdgcn_s_setprio(1);
#pragma unroll
            for (int cc = 0; cc < 4; ++cc) {
                f32x4 sx = {};
#pragma unroll
                for (int kc = 0; kc < 6; ++kc) {
                    short8 kf = *(const short8*)&lK[(cc * 16 + l16) * 200 + kc * 32 + quad * 8];
                    sx = __builtin_amdgcn_mfma_f32_16x16x32_bf16(qf[kc], kf, sx, 0, 0, 0);
                }
                s4[cc] = sx;
            }
            __builtin_amdgcn_s_setprio(0);

            // causal mask; rows ir = iw + quad*4 + r, cols j0 + cc*16 + l16
            float sv[4][4];
#pragma unroll
            for (int cc = 0; cc < 4; ++cc)
#pragma unroll
                for (int r = 0; r < 4; ++r) {
                    int ir = iw + quad * 4 + r;
                    sv[cc][r] = (j0 + cc * 16 + l16 <= ir) ? s4[cc][r] : -1e30f;
                }
            float tm[4];
#pragma unroll
            for (int r = 0; r < 4; ++r)
                tm[r] = fmaxf(fmaxf(sv[0][r], sv[1][r]), fmaxf(sv[2][r], sv[3][r]));
#pragma unroll
            for (int m = 1; m < 16; m <<= 1)
#pragma unroll
                for (int r = 0; r < 4; ++r) tm[r] = fmaxf(tm[r], __shfl_xor(tm[r], m));
            float al[4];
#pragma unroll
            for (int r = 0; r < 4; ++r) {
                float mn = fmaxf(mr[r], tm[r]);
                al[r] = __expf(mr[r] - mn);
                mr[r] = mn;
            }
            float p[4][4], ps[4] = {0.f, 0.f, 0.f, 0.f};
#pragma unroll
            for (int cc = 0; cc < 4; ++cc)
#pragma unroll
                for (int r = 0; r < 4; ++r) {
                    p[cc][r] = __expf(sv[cc][r] - mr[r]);
                    ps[r] += p[cc][r];
                }
#pragma unroll
            for (int m = 1; m < 16; m <<= 1)
#pragma unroll
                for (int r = 0; r < 4; ++r) ps[r] += __shfl_xor(ps[r], m);
#pragma unroll
            for (int r = 0; r < 4; ++r) lr[r] = lr[r] * al[r] + ps[r];
#pragma unroll
            for (int dc = 0; dc < 8; ++dc)
#pragma unroll
                for (int r = 0; r < 4; ++r) O8[dc][r] *= al[r];
            // P (C layout) -> LDS -> A-layout frags (k = 0..31, 32..63)
#pragma unroll
            for (int cc = 0; cc < 4; ++cc)
#pragma unroll
                for (int r = 0; r < 4; ++r)
                    lP[w][(quad * 4 + r) * 72 + cc * 16 + l16] = f2b(p[cc][r]);
            short8 pf0 = *(const short8*)&lP[w][l16 * 72 + quad * 8];
            short8 pf1 = *(const short8*)&lP[w][l16 * 72 + 32 + quad * 8];
            // O += P V  (B-frag from Vt rows: n=d, k=kv-pos)
            __builtin_amdgcn_s_setprio(1);
#pragma unroll
            for (int dc = 0; dc < 8; ++dc) {
                short8 vf0 = *(const short8*)&lVt[(dc * 16 + l16) * 72 + quad * 8];
                short8 vf1 = *(const short8*)&lVt[(dc * 16 + l16) * 72 + 32 + quad * 8];
                O8[dc] = __builtin_amdgcn_mfma_f32_16x16x32_bf16(pf0, vf0, O8[dc], 0, 0, 0);
                O8[dc] = __builtin_amdgcn_mfma_f32_16x16x32_bf16(pf1, vf1, O8[dc], 0, 0, 0);
            }
            __builtin_amdgcn_s_setprio(0);
        }
        // epilogue: normalize, write fp16
        float inv[4];
#pragma unroll
        for (int r = 0; r < 4; ++r) inv[r] = 1.f / fmaxf(lr[r], 1e-30f);
#pragma unroll
        for (int dc = 0; dc < 8; ++dc)
#pragma unroll
            for (int r = 0; r < 4; ++r) {
                int ir = iw + quad * 4 + r;
                atf[((size_t)(b * S_ + ir)) * 2048 + h * 128 + dc * 16 + l16] =
                    (_Float16)cl(O8[dc][r] * inv[r]);
            }
    }
}

// ---------------------------------------------------------------------------
extern "C" void kernel_launch(void* const* d_in, const int* in_sizes, int n_in,
                              void* d_out, int out_size, void* d_ws, size_t ws_size,
                              hipStream_t stream) {
    const float* x     = (const float*)d_in[0];
    const float* cosc  = (const float*)d_in[1];
    const float* sinc  = (const float*)d_in[2];
    const int*   pos   = (const int*)d_in[3];
    // d_in[4] = attn_mask (causal tril) -- implemented analytically
    const float* W_DKV = (const float*)d_in[5];
    const float* W_UK  = (const float*)d_in[6];
    const float* W_UV  = (const float*)d_in[7];
    const float* W_DQ  = (const float*)d_in[8];
    const float* W_UQ  = (const float*)d_in[9];
    const float* W_KR  = (const float*)d_in[10];
    const float* W_QR  = (const float*)d_in[11];
    const float* W_O   = (const float*)d_in[12];
    (void)ws_size;

    float* outp      = (float*)d_out;            // [B,S,2048]
    float* ckv_out   = outp + 8388608;           // [B,S,512]
    float* krope_out = outp + 10485760;          // [B,NKV,S,64]

    // ---- workspace (~190 MB; harness provided >=241 MB in round 1) ----
    char* w = (char*)d_ws;
    auto alloc = [&](size_t bytes) { char* p = w; w += bytes; return p; };
    u16*      xh    = (u16*)alloc(16777216);      // x bf16 hi [4096][2048]
    u16*      xl    = (u16*)alloc(16777216);      // x bf16 lo
    _Float16* xf    = (_Float16*)alloc(16777216); // x fp16
    float*    Cdk   = (float*)alloc(12582912);    // [4096][768] c_kv|krr fp32
    _Float16* ckf   = (_Float16*)alloc(4194304);  // c_kv fp16 [4096][512]
    _Float16* cqf   = (_Float16*)alloc(12582912); // c_q fp16 [4096][1536]
    u16*      qc16  = (u16*)alloc(16777216);      // Q content bf16 pre-scaled [4096][2048]
    float*    qrr   = (float*)alloc(16777216);    // Q rope fp32 [4096][1024]
    float*    kcvb  = (float*)alloc(16777216);    // [4096][1024] Kcontent|V fp32
    u16*      Kp    = (u16*)alloc(6291456);       // [8][2048][192] bf16
    u16*      Vt    = (u16*)alloc(4194304);       // [8][128][2048] bf16
    _Float16* atf   = (_Float16*)alloc(16777216); // attn out fp16 [4096][2048]
    u16* Wdkh  = (u16*)alloc(3145728);            // [768][2048] bf16 hi (DKV|KR)
    u16* Wdkl  = (u16*)alloc(3145728);
    _Float16* Wdqf  = (_Float16*)alloc(6291456);  // [1536][2048]
    _Float16* Wuqf  = (_Float16*)alloc(6291456);  // [2048][1536]
    _Float16* Wqrf  = (_Float16*)alloc(4194304);  // [1024][2048]
    _Float16* Wukvf = (_Float16*)alloc(1048576);  // [1024][512]  (UK|UV)
    _Float16* Wof   = (_Float16*)alloc(8388608);  // [2048][2048]

    const float sc = 0.07216878364870322f;        // 1/sqrt(192)
    const dim3 tb(32, 8);

    // input / weight prep
    x_prep<<<4096, 256, 0, stream>>>(x, xh, xl, xf);
    wt_split<<<dim3(64, 16), tb, 0, stream>>>(W_DKV, Wdkh, Wdkl, 2048, 512);
    wt_split<<<dim3(64, 8),  tb, 0, stream>>>(W_KR,  Wdkh + 512 * 2048, Wdkl + 512 * 2048, 2048, 256);
    wt_f16<<<dim3(64, 48), tb, 0, stream>>>(W_DQ, Wdqf, 2048, 1536);
    wt_f16<<<dim3(48, 64), tb, 0, stream>>>(W_UQ, Wuqf, 1536, 2048);
    wt_f16<<<dim3(64, 32), tb, 0, stream>>>(W_QR, Wqrf, 2048, 1024);
    wt_f16<<<dim3(16, 16), tb, 0, stream>>>(W_UK, Wukvf, 512, 512);
    wt_f16<<<dim3(16, 16), tb, 0, stream>>>(W_UV, Wukvf + 512 * 512, 512, 512);
    wt_f16<<<dim3(64, 64), tb, 0, stream>>>(W_O,  Wof, 2048, 2048);

    // exact path (direct outputs): c_kv | K-rope-raw in one GEMM
    gemm_bf3<<<dim3(6, 32), 256, 0, stream>>>(xh, xl, Wdkh, Wdkl, Cdk, 768, 2048);
    ckv_post<<<1024, 256, 0, stream>>>(Cdk, ckv_out, ckf);        // Output 1 + fp16 copy

    // fp16 attention-path projections
    gemm_f16<<<dim3(12, 32), 256, 0, stream>>>(xf,  Wdqf,  nullptr, cqf,  nullptr, 1.f, 1536, 2048); // c_q
    gemm_f16<<<dim3(16, 32), 256, 0, stream>>>(cqf, Wuqf,  nullptr, nullptr, qc16, sc,  2048, 1536); // Q content (bf16, pre-scaled)
    gemm_f16<<<dim3(8, 32),  256, 0, stream>>>(xf,  Wqrf,  qrr,  nullptr, nullptr, 1.f, 1024, 2048); // Q rope raw
    gemm_f16<<<dim3(8, 32),  256, 0, stream>>>(ckf, Wukvf, kcvb, nullptr, nullptr, 1.f, 1024, 512);  // Kcontent | V

    // rope
    rope_q_inplace<<<8192, 256, 0, stream>>>(qrr, cosc, sinc, pos);
    rope_k<<<2048, 256, 0, stream>>>(Cdk + 512, 768, cosc, sinc, pos, krope_out);  // Output 2

    // pack K / V for MFMA attention
    pack_k<<<1536, 256, 0, stream>>>(kcvb, 1024, krope_out, Kp);
    transpose_vt<<<dim3(64, 4, 8), tb, 0, stream>>>(kcvb + 512, 1024, Vt);

    // attention + output projection
    attn_mfma<<<dim3(16, 16, 2), 256, 0, stream>>>(qc16, qrr, Kp, Vt, atf);
    gemm_f16<<<dim3(16, 32), 256, 0, stream>>>(atf, Wof, outp, nullptr, nullptr, 1.f, 2048, 2048);   // Output 0
}